// Round 16
// baseline (504.627 us; speedup 1.0000x reference)
//
#include <hip/hip_runtime.h>
#include <hip/hip_bf16.h>

typedef float f32x4 __attribute__((ext_vector_type(4)));
typedef short s16x8 __attribute__((ext_vector_type(8)));
typedef __hip_bfloat16 bf16;

#define NB 32
#define CB 512
#define DB 2048
#define QB 64
#define HB 16
#define DHB 128

static __device__ __forceinline__ void gload16(const void* g, void* l) {
  __builtin_amdgcn_global_load_lds(
      (const __attribute__((address_space(1))) void*)g,
      (__attribute__((address_space(3))) void*)l, 16, 0, 0);
}

static __device__ __forceinline__ unsigned short f2bf(float f) {
  bf16 b = __float2bfloat16(f);
  return *reinterpret_cast<unsigned short*>(&b);
}

static __device__ __forceinline__ float gelu_f(float z) {
  return 0.5f * z * (1.0f + erff(z * 0.7071067811865475f));
}

#define BAR2 do { asm volatile("" ::: "memory"); __builtin_amdgcn_s_barrier(); asm volatile("" ::: "memory"); } while (0)
#define VM2  asm volatile("s_waitcnt vmcnt(2)" ::: "memory")
#define VM0  asm volatile("s_waitcnt vmcnt(0)" ::: "memory")

// ---------------- fused convert+pool, float4 loads / ushort4 stores ----------------
__global__ void k_convpool(const float* __restrict__ x, bf16* __restrict__ x_bf,
                           bf16* __restrict__ tokens) {
  const int d0 = blockIdx.x * 1024 + threadIdx.x * 4;
  const int q = blockIdx.y, n = blockIdx.z;
  const size_t base = ((size_t)(n * CB + q * 8)) * DB + d0;
  float s0 = 0.f, s1 = 0.f, s2 = 0.f, s3 = 0.f;
#pragma unroll
  for (int j = 0; j < 8; ++j) {
    float4 v = *(const float4*)(x + base + (size_t)j * DB);
    s0 += v.x; s1 += v.y; s2 += v.z; s3 += v.w;
    ushort4 o; o.x = f2bf(v.x); o.y = f2bf(v.y); o.z = f2bf(v.z); o.w = f2bf(v.w);
    *(ushort4*)((unsigned short*)x_bf + base + (size_t)j * DB) = o;
  }
  ushort4 p;
  p.x = f2bf(s0 * 0.125f); p.y = f2bf(s1 * 0.125f);
  p.z = f2bf(s2 * 0.125f); p.w = f2bf(s3 * 0.125f);
  *(ushort4*)((unsigned short*)tokens + (size_t)2 * (n * QB + q) * DB + d0) = p;
}

// ---------------- merged convert f32 -> bf16 (two buffers, one launch) ----------------
__global__ void k_convert2(const float* __restrict__ a, unsigned short* __restrict__ oa, int na4,
                           const float* __restrict__ b, unsigned short* __restrict__ ob, int nb4) {
  int stride = gridDim.x * blockDim.x;
  int tot = na4 + nb4;
  for (int i = blockIdx.x * blockDim.x + threadIdx.x; i < tot; i += stride) {
    const float* src; unsigned short* dst; int k;
    if (i < na4) { src = a; dst = oa; k = i; } else { src = b; dst = ob; k = i - na4; }
    float4 v = ((const float4*)src)[k];
    ushort4 o;
    o.x = f2bf(v.x); o.y = f2bf(v.y); o.z = f2bf(v.z); o.w = f2bf(v.w);
    ((ushort4*)dst)[k] = o;
  }
}

// ---------------- gating (reads interleaved tokens, row 2t) ----------------
__global__ void k_gate(const bf16* __restrict__ tokens, const float* __restrict__ wg,
                       float* __restrict__ gates, float* __restrict__ gsum) {
  int t = blockIdx.x * 4 + (threadIdx.x >> 6);
  int lane = threadIdx.x & 63;
  const bf16* row = tokens + (size_t)2 * t * DB;
  float z0 = 0.f, z1 = 0.f;
  for (int d = lane; d < DB; d += 64) {
    float v = __bfloat162float(row[d]);
    z0 += v * wg[d * 2];
    z1 += v * wg[d * 2 + 1];
  }
#pragma unroll
  for (int m = 32; m; m >>= 1) { z0 += __shfl_xor(z0, m, 64); z1 += __shfl_xor(z1, m, 64); }
  if (lane == 0) {
    float mx = fmaxf(z0, z1);
    float e0 = __expf(z0 - mx), e1 = __expf(z1 - mx);
    float s = e0 + e1;
    float p0 = e0 / s, p1 = e1 / s;
    float inv = 1.0f / (p0 + p1 + 1e-6f);
    float g0 = p0 * inv, g1 = p1 * inv;
    gates[t * 2] = g0;
    gates[t * 2 + 1] = g1;
    gsum[t] = g0 + g1;
  }
}

// ---------------- batched transpose+convert: float4 loads, ushort4 stores ----------------
struct TP5 { const float* s[5]; bf16* d[5]; };
__global__ void k_transpose5(TP5 p) {
  __shared__ float t[32][33];
  const float* W = p.s[blockIdx.z];
  bf16* WT = p.d[blockIdx.z];
  int bx = blockIdx.x * 32;
  int by = blockIdx.y * 32;
  int tx = threadIdx.x;   // 0..7
  int ty = threadIdx.y;   // 0..31
  float4 v = *(const float4*)(W + (size_t)(by + ty) * DB + bx + tx * 4);
  t[ty][tx * 4 + 0] = v.x; t[ty][tx * 4 + 1] = v.y;
  t[ty][tx * 4 + 2] = v.z; t[ty][tx * 4 + 3] = v.w;
  __syncthreads();
  ushort4 o;
  o.x = f2bf(t[tx * 4 + 0][ty]);
  o.y = f2bf(t[tx * 4 + 1][ty]);
  o.z = f2bf(t[tx * 4 + 2][ty]);
  o.w = f2bf(t[tx * 4 + 3][ty]);
  *(ushort4*)((unsigned short*)WT + (size_t)(bx + ty) * DB + by + tx * 4) = o;
}

// ---------------- q-proj partial reduce ----------------
__global__ void k_qreduce(const float* __restrict__ qp, const float* __restrict__ bq,
                          bf16* __restrict__ qproj) {
  int i = blockIdx.x * 256 + threadIdx.x;
  const int S = QB * DB;
  float s = qp[i] + qp[i + S] + qp[i + 2 * S] + qp[i + 3 * S] + bq[i & (DB - 1)];
  qproj[i] = __float2bfloat16(s);
}

// ======== 256x256 GEMM, single-barrier K-tile, front-loaded staging ========
// Per K-tile: p0 stages A-hi,B-hi(t+1); p1 stages A-lo,B-lo(t+1); p2/p3 compute only;
// one vmcnt(0)+barrier at tile end (all loads >= 2.5 phases in flight by then).
// EPI: 0 = bf16 out, 1 = GELU->bf16, 2 = f32 out
template <int EPI>
__global__ __launch_bounds__(512, 2) void k_gemm256(
    const bf16* __restrict__ A, int lda, long long sAb,
    const bf16* __restrict__ BT, int ldb, long long sBb,
    const float* __restrict__ bias, void* __restrict__ Cout, int ldc, long long sCb,
    int K, int ntiles) {
  __shared__ __align__(16) bf16 lds[2][2][256 * 64];

  int bid = blockIdx.x;
  { int c = gridDim.x >> 3; bid = (bid & 7) * c + (bid >> 3); }
  const int m0 = (bid / ntiles) * 256;
  const int n0 = (bid % ntiles) * 256;
  const int z = blockIdx.z;
  A += (size_t)z * sAb;
  BT += (size_t)z * sBb;

  const int tid = threadIdx.x;
  const int l = tid & 63, w = tid >> 6;
  const int wr = w >> 2, wc = w & 3;
  const int fr = l & 15, fg = l >> 4;

  const int rloc = w * 8 + (l >> 3);
  const int cswz = ((l & 7) ^ (l >> 3)) * 8;
  const bf16* Asw = A + cswz;
  const bf16* Bsw = BT + cswz;

  int rbA[4], rbB[4], ckb[2];
#pragma unroll
  for (int mi = 0; mi < 4; ++mi) rbA[mi] = (wr * 64 + mi * 16 + fr) * 128;
#pragma unroll
  for (int ni = 0; ni < 4; ++ni) rbB[ni] = ((ni >> 1) * 128 + wc * 32 + (ni & 1) * 16 + fr) * 128;
#pragma unroll
  for (int kk = 0; kk < 2; ++kk) ckb[kk] = ((kk * 4 + fg) ^ (fr & 7)) * 16;

  f32x4 acc[8][4] = {};
  s16x8 af[4], bfr[4][2];

  auto stg = [&](const bf16* srcsw, int ld, int row0, int kcol, char* dst) {
    gload16(srcsw + (size_t)(row0 + rloc) * ld + kcol, dst + w * 1024);
    gload16(srcsw + (size_t)(row0 + 64 + rloc) * ld + kcol, dst + 8192 + w * 1024);
  };

  // prologue: stage tile 0 fully into buf0
  stg(Asw, lda, m0, 0, (char*)&lds[0][0][0]);
  stg(Bsw, ldb, n0, 0, (char*)&lds[0][1][0]);
  stg(Bsw, ldb, n0 + 128, 0, (char*)&lds[0][1][0] + 16384);
  stg(Asw, lda, m0 + 128, 0, (char*)&lds[0][0][0] + 16384);
  VM0;
  BAR2;

  const int NT = K >> 6;
  for (int t = 0; t < NT; ++t) {
    const int buf = t & 1;
    const char* Ab = (const char*)&lds[buf][0][0];
    const char* Bb = (const char*)&lds[buf][1][0];
    char* As = (char*)&lds[buf ^ 1][0][0];
    char* Bs = (char*)&lds[buf ^ 1][1][0];
    const int kn = (t + 1 < NT ? (t + 1) : 0) << 6;

    // p0: stage A-hi,B-hi(t+1); Mlo x Nall x k0
    stg(Asw, lda, m0 + 128, kn, As + 16384);
    stg(Bsw, ldb, n0 + 128, kn, Bs + 16384);
#pragma unroll
    for (int mi = 0; mi < 4; ++mi) af[mi] = *(const s16x8*)(Ab + rbA[mi] + ckb[0]);
#pragma unroll
    for (int ni = 0; ni < 4; ++ni) bfr[ni][0] = *(const s16x8*)(Bb + rbB[ni] + ckb[0]);
    __builtin_amdgcn_s_setprio(1);
#pragma unroll
    for (int mi = 0; mi < 4; ++mi)
#pragma unroll
      for (int ni = 0; ni < 4; ++ni)
        acc[mi][ni] = __builtin_amdgcn_mfma_f32_16x16x32_bf16(af[mi], bfr[ni][0], acc[mi][ni], 0, 0, 0);
    __builtin_amdgcn_s_setprio(0);

    // p1: stage A-lo,B-lo(t+1); Mhi x Nall x k0  (A-hi(t) already drained at prior tile-end)
    stg(Asw, lda, m0, kn, As);
    stg(Bsw, ldb, n0, kn, Bs);
#pragma unroll
    for (int mi = 0; mi < 4; ++mi) af[mi] = *(const s16x8*)(Ab + 16384 + rbA[mi] + ckb[0]);
    __builtin_amdgcn_s_setprio(1);
#pragma unroll
    for (int mi = 0; mi < 4; ++mi)
#pragma unroll
      for (int ni = 0; ni < 4; ++ni)
        acc[4 + mi][ni] = __builtin_amdgcn_mfma_f32_16x16x32_bf16(af[mi], bfr[ni][0], acc[4 + mi][ni], 0, 0, 0);
    __builtin_amdgcn_s_setprio(0);

    // p2: Mlo x Nall x k1
#pragma unroll
    for (int mi = 0; mi < 4; ++mi) af[mi] = *(const s16x8*)(Ab + rbA[mi] + ckb[1]);
#pragma unroll
    for (int ni = 0; ni < 4; ++ni) bfr[ni][1] = *(const s16x8*)(Bb + rbB[ni] + ckb[1]);
    __builtin_amdgcn_s_setprio(1);
#pragma unroll
    for (int mi = 0; mi < 4; ++mi)
#pragma unroll
      for (int ni = 0; ni < 4; ++ni)
        acc[mi][ni] = __builtin_amdgcn_mfma_f32_16x16x32_bf16(af[mi], bfr[ni][1], acc[mi][ni], 0, 0, 0);
    __builtin_amdgcn_s_setprio(0);

    // p3: Mhi x Nall x k1
#pragma unroll
    for (int mi = 0; mi < 4; ++mi) af[mi] = *(const s16x8*)(Ab + 16384 + rbA[mi] + ckb[1]);
    __builtin_amdgcn_s_setprio(1);
#pragma unroll
    for (int mi = 0; mi < 4; ++mi)
#pragma unroll
      for (int ni = 0; ni < 4; ++ni)
        acc[4 + mi][ni] = __builtin_amdgcn_mfma_f32_16x16x32_bf16(af[mi], bfr[ni][1], acc[4 + mi][ni], 0, 0, 0);
    __builtin_amdgcn_s_setprio(0);

    // tile end: all 8 loads issued >= 2.5 phases ago -> drain is cheap
    VM0;
    BAR2;
  }

#pragma unroll
  for (int mi = 0; mi < 8; ++mi) {
    int row = m0 + (mi >> 2) * 128 + wr * 64 + (mi & 3) * 16 + fg * 4;
#pragma unroll
    for (int ni = 0; ni < 4; ++ni) {
      int col = n0 + (ni >> 1) * 128 + wc * 32 + (ni & 1) * 16 + fr;
      float bv = bias ? bias[col] : 0.f;
#pragma unroll
      for (int j = 0; j < 4; ++j) {
        float v = acc[mi][ni][j] + bv;
        size_t o = (size_t)z * sCb + (size_t)(row + j) * ldc + col;
        if (EPI == 0) {
          ((bf16*)Cout)[o] = __float2bfloat16(v);
        } else if (EPI == 1) {
          ((bf16*)Cout)[o] = __float2bfloat16(gelu_f(v));
        } else {
          ((float*)Cout)[o] = v;
        }
      }
    }
  }
}

// ======== 128x256 GEMM (BM=128), R3-pattern, 16x16 MFMA (unchanged) ========
template <int EPI>
__global__ __launch_bounds__(512, 2) void k_gemmH(
    const bf16* __restrict__ A, int lda,
    const bf16* __restrict__ BT, int ldb,
    const float* __restrict__ bias, void* __restrict__ Cout, int ldc,
    int K, int ntiles, const float* __restrict__ gates) {
  __shared__ __align__(16) bf16 ldsA[2][128 * 64];
  __shared__ __align__(16) bf16 ldsB[2][256 * 64];

  int bid = blockIdx.x;
  { int c = gridDim.x >> 3; bid = (bid & 7) * c + (bid >> 3); }
  const int m0 = (bid / ntiles) * 128;
  const int n0 = (bid % ntiles) * 256;

  const int tid = threadIdx.x;
  const int l = tid & 63, w = tid >> 6;
  const int wr = w >> 2, wc = w & 3;
  const int fr = l & 15, fg = l >> 4;

  const int rloc = w * 8 + (l >> 3);
  const int cswz = ((l & 7) ^ (l >> 3)) * 8;
  const bf16* Asw = A + cswz;
  const bf16* Bsw = BT + cswz;

  int rbA[4], rbB[4], ckb[2];
#pragma unroll
  for (int mi = 0; mi < 4; ++mi) rbA[mi] = (wr * 64 + mi * 16 + fr) * 128;
#pragma unroll
  for (int ni = 0; ni < 4; ++ni) rbB[ni] = ((ni >> 1) * 128 + wc * 32 + (ni & 1) * 16 + fr) * 128;
#pragma unroll
  for (int kk = 0; kk < 2; ++kk) ckb[kk] = ((kk * 4 + fg) ^ (fr & 7)) * 16;

  f32x4 acc[4][4] = {};
  s16x8 af[4], blo[2][2], bhi[2][2];

  auto stg = [&](const bf16* srcsw, int ld, int row0, int kcol, char* dst) {
    gload16(srcsw + (size_t)(row0 + rloc) * ld + kcol, dst + w * 1024);
    gload16(srcsw + (size_t)(row0 + 64 + rloc) * ld + kcol, dst + 8192 + w * 1024);
  };

  stg(Asw, lda, m0, 0, (char*)&ldsA[0][0]);
  stg(Bsw, ldb, n0, 0, (char*)&ldsB[0][0]);
  stg(Bsw, ldb, n0 + 128, 0, (char*)&ldsB[0][0] + 16384);
  asm volatile("s_waitcnt vmcnt(0)" ::: "memory");
  BAR2;

  const int NT = K >> 6;
  for (int t = 0; t < NT; ++t) {
    const int buf = t & 1;
    const char* Ab = (const char*)&ldsA[buf][0];
    const char* Bb = (const char*)&ldsB[buf][0];
    char* As = (char*)&ldsA[buf ^ 1][0];
    char* Bs = (char*)&ldsB[buf ^ 1][0];
    const int kn = (t + 1 < NT ? (t + 1) : 0) << 6;

    stg(Asw, lda, m0, kn, As);
#pragma unroll
    for (int mi = 0; mi < 4; ++mi) af[mi] = *(const s16x8*)(Ab + rbA[mi] + ckb[0]);
#pragma unroll
    for (int ni = 0; ni < 2; ++ni) blo[ni][0] = *(const s16x8*)(Bb + rbB[ni] + ckb[0]);
    __builtin_amdgcn_s_setprio(1);
#pragma unroll
    for (int mi = 0; mi < 4; ++mi)
#pragma unroll
      for (int ni = 0; ni < 2; ++ni)
        acc[mi][ni] = __builtin_amdgcn_mfma_f32_16x16x32_bf16(af[mi], blo[ni][0], acc[mi][ni], 0, 0, 0);
    __builtin_amdgcn_s_setprio(0);
    VM2;
    BAR2;

    stg(Bsw, ldb, n0, kn, Bs);
#pragma unroll
    for (int ni = 0; ni < 2; ++ni) bhi[ni][0] = *(const s16x8*)(Bb + rbB[2 + ni] + ckb[0]);
    __builtin_amdgcn_s_setprio(1);
#pragma unroll
    for (int mi = 0; mi < 4; ++mi)
#pragma unroll
      for (int ni = 0; ni < 2; ++ni)
        acc[mi][2 + ni] = __builtin_amdgcn_mfma_f32_16x16x32_bf16(af[mi], bhi[ni][0], acc[mi][2 + ni], 0, 0, 0);
    __builtin_amdgcn_s_setprio(0);

    stg(Bsw, ldb, n0 + 128, kn, Bs + 16384);
#pragma unroll
    for (int mi = 0; mi < 4; ++mi) af[mi] = *(const s16x8*)(Ab + rbA[mi] + ckb[1]);
#pragma unroll
    for (int ni = 0; ni < 2; ++ni) blo[ni][1] = *(const s16x8*)(Bb + rbB[ni] + ckb[1]);
    __builtin_amdgcn_s_setprio(1);
#pragma unroll
    for (int mi = 0; mi < 4; ++mi)
#pragma unroll
      for (int ni = 0; ni < 2; ++ni)
        acc[mi][ni] = __builtin_amdgcn_mfma_f32_16x16x32_bf16(af[mi], blo[ni][1], acc[mi][ni], 0, 0, 0);
    __builtin_amdgcn_s_setprio(0);

#pragma unroll
    for (int ni = 0; ni < 2; ++ni) bhi[ni][1] = *(const s16x8*)(Bb + rbB[2 + ni] + ckb[1]);
    __builtin_amdgcn_s_setprio(1);
#pragma unroll
    for (int mi = 0; mi < 4; ++mi)
#pragma unroll
      for (int ni = 0; ni < 2; ++ni)
        acc[mi][2 + ni] = __builtin_amdgcn_mfma_f32_16x16x32_bf16(af[mi], bhi[ni][1], acc[mi][2 + ni], 0, 0, 0);
    __builtin_amdgcn_s_setprio(0);
    VM2;
    BAR2;
  }

#pragma unroll
  for (int mi = 0; mi < 4; ++mi) {
    int row = m0 + wr * 64 + mi * 16 + fg * 4;
#pragma unroll
    for (int ni = 0; ni < 4; ++ni) {
      int col = n0 + (ni >> 1) * 128 + wc * 32 + (ni & 1) * 16 + fr;
      float bv = bias ? bias[col] : 0.f;
      if (EPI == 3) {
#pragma unroll
        for (int j = 0; j < 4; j += 2) {
          int tk = (row + j) >> 1;
          float g0 = gates[tk * 2], g1 = gates[tk * 2 + 1];
          float v0 = gelu_f(acc[mi][ni][j] + bv);
          float v1 = gelu_f(acc[mi][ni][j + 1] + bv);
          ((bf16*)Cout)[(size_t)tk * ldc + col] = __float2bfloat16(g0 * v0 + g1 * v1);
        }
      } else {
#pragma unroll
        for (int j = 0; j < 4; ++j) {
          float v = acc[mi][ni][j] + bv;
          size_t o = (size_t)(row + j) * ldc + col;
          if (EPI == 0) ((bf16*)Cout)[o] = __float2bfloat16(v);
          else ((float*)Cout)[o] = v;
        }
      }
    }
  }
}

// ---------------- 128x128 GEMM ----------------
template <int EPI>
__global__ __launch_bounds__(256) void k_gemm(
    const bf16* __restrict__ A, int lda, long long sAb,
    const bf16* __restrict__ BT, int ldb, long long sBb,
    const float* __restrict__ bias, void* __restrict__ Cout, int ldc, long long sCb,
    int M, int K, const float* __restrict__ gsum) {
  __shared__ bf16 As[128 * 32];
  __shared__ bf16 Bs[128 * 32];
  const int z = blockIdx.z;
  A += (size_t)z * sAb;
  BT += (size_t)z * sBb;
  const int tid = threadIdx.x;
  const int lane = tid & 63, w = tid >> 6;
  const int m0 = blockIdx.x * 128, n0 = blockIdx.y * 128;
  const int wm = (w >> 1) * 64, wn = (w & 1) * 64;
  f32x4 acc[4][4] = {};

  const int srow = tid >> 2;
  const int scol = (tid & 3) * 8;
  int gr0 = m0 + srow;       if (gr0 > M - 1) gr0 = M - 1;
  int gr1 = m0 + 64 + srow;  if (gr1 > M - 1) gr1 = M - 1;
  const bf16* ag0 = A + (size_t)gr0 * lda + scol;
  const bf16* ag1 = A + (size_t)gr1 * lda + scol;
  const bf16* bg0 = BT + (size_t)(n0 + srow) * ldb + scol;
  const bf16* bg1 = BT + (size_t)(n0 + 64 + srow) * ldb + scol;
  char* lA = (char*)As + w * 1024;
  char* lB = (char*)Bs + w * 1024;

  const int fr = lane & 15, fk = (lane >> 4) * 8;

  for (int k0 = 0; k0 < K; k0 += 32) {
    __syncthreads();
    gload16(ag0 + k0, lA);
    gload16(ag1 + k0, lA + 4096);
    gload16(bg0 + k0, lB);
    gload16(bg1 + k0, lB + 4096);
    __syncthreads();
    s16x8 af[4], bfr[4];
#pragma unroll
    for (int i = 0; i < 4; ++i)
      af[i] = *(const s16x8*)(As + (wm + i * 16 + fr) * 32 + fk);
#pragma unroll
    for (int i = 0; i < 4; ++i)
      bfr[i] = *(const s16x8*)(Bs + (wn + i * 16 + fr) * 32 + fk);
#pragma unroll
    for (int mi = 0; mi < 4; ++mi)
#pragma unroll
      for (int ni = 0; ni < 4; ++ni)
        acc[mi][ni] = __builtin_amdgcn_mfma_f32_16x16x32_bf16(af[mi], bfr[ni], acc[mi][ni], 0, 0, 0);
  }

  const int fg4 = (lane >> 4) * 4;
#pragma unroll
  for (int mi = 0; mi < 4; ++mi) {
#pragma unroll
    for (int ni = 0; ni < 4; ++ni) {
      int col = n0 + wn + ni * 16 + fr;
      float bv = bias ? bias[col] : 0.f;
#pragma unroll
      for (int j = 0; j < 4; ++j) {
        int r = m0 + wm + mi * 16 + fg4 + j;
        if (r >= M) continue;
        size_t o = (size_t)z * sCb + (size_t)r * ldc + col;
        if (EPI == 0) {
          ((bf16*)Cout)[o] = __float2bfloat16(acc[mi][ni][j] + bv);
        } else if (EPI == 1) {
          ((bf16*)Cout)[o] = __float2bfloat16(gelu_f(acc[mi][ni][j] + bv));
        } else if (EPI == 2) {
          ((float*)Cout)[o] = acc[mi][ni][j] + bv;
        } else {
          ((float*)Cout)[o] = acc[mi][ni][j] + gsum[r] * bv;
        }
      }
    }
  }
}

// ---------------- attention per (n,h): XOR-swizzled LDS ----------------
__global__ __launch_bounds__(256) void k_attn(
    const bf16* __restrict__ S, const bf16* __restrict__ Vg, bf16* __restrict__ ctxg) {
  __shared__ bf16 vt[128 * 64];
  __shared__ bf16 pb[4][16 * 64];
  const int nh = blockIdx.x;
  const int n = nh >> 4, h = nh & 15;
  const int tid = threadIdx.x, lane = tid & 63, w = tid >> 6;
  const int fr = lane & 15, fg = lane >> 4;

  f32x4 ctx[8] = {};
  float mrow[4], lrow[4];
#pragma unroll
  for (int j = 0; j < 4; ++j) { mrow[j] = -1e30f; lrow[j] = 0.f; }

  const bf16* Srow = S + ((size_t)n * (HB * QB) + h * QB) * CB;
  const bf16* Vbase = Vg + (size_t)(n * CB) * DB + h * DHB;
  const float SC = 0.08838834764831845f;

  const int krow = tid >> 4;
  const int kcol = (tid & 15) * 8;

  for (int c0 = 0; c0 < CB; c0 += 64) {
    __syncthreads();
#pragma unroll
    for (int jj = 0; jj < 4; ++jj) {
      int cc = jj * 16 + krow;
      s16x8 vv = *(const s16x8*)(Vbase + (size_t)(c0 + cc) * DB + kcol);
#pragma unroll
      for (int i = 0; i < 8; ++i) {
        int d = kcol + i;
        int sc = cc ^ ((((d & 7) ^ ((d >> 3) & 7))) << 3);
        vt[(size_t)d * 64 + sc] = ((const bf16*)&vv)[i];
      }
    }

    f32x4 s4[4];
#pragma unroll
    for (int ci = 0; ci < 4; ++ci)
#pragma unroll
      for (int j = 0; j < 4; ++j)
        s4[ci][j] = __bfloat162float(Srow[(size_t)(w * 16 + fg * 4 + j) * CB + c0 + ci * 16 + fr]);

#pragma unroll
    for (int j = 0; j < 4; ++j) {
      float m = fmaxf(fmaxf(s4[0][j], s4[1][j]), fmaxf(s4[2][j], s4[3][j])) * SC;
#pragma unroll
      for (int msk = 1; msk < 16; msk <<= 1) m = fmaxf(m, __shfl_xor(m, msk, 16));
      float newm = fmaxf(mrow[j], m);
      float resc = __expf(mrow[j] - newm);
      mrow[j] = newm;
      float rsum = 0.f;
      int q = fg * 4 + j;
      int qx = ((q & 7) ^ (q >> 3)) << 3;
#pragma unroll
      for (int ci = 0; ci < 4; ++ci) {
        float p = __expf(s4[ci][j] * SC - newm);
        rsum += p;
        pb[w][q * 64 + ((ci * 16 + fr) ^ qx)] = __float2bfloat16(p);
      }
#pragma unroll
      for (int msk = 1; msk < 16; msk <<= 1) rsum += __shfl_xor(rsum, msk, 16);
      lrow[j] = lrow[j] * resc + rsum;
#pragma unroll
      for (int ni = 0; ni < 8; ++ni) ctx[ni][j] = ctx[ni][j] * resc;
    }
    __syncthreads();

#pragma unroll
    for (int kk2 = 0; kk2 < 2; ++kk2) {
      int pqx = ((fr & 7) ^ (fr >> 3)) << 3;
      s16x8 pa = *(const s16x8*)(&pb[w][fr * 64 + ((kk2 * 32 + fg * 8) ^ pqx)]);
#pragma unroll
      for (int ni = 0; ni < 8; ++ni) {
        int d = ni * 16 + fr;
        int dx = (((d & 7) ^ ((d >> 3) & 7))) << 3;
        s16x8 bv = *(const s16x8*)(vt + (size_t)d * 64 + ((kk2 * 32 + fg * 8) ^ dx));
        ctx[ni] = __builtin_amdgcn_mfma_f32_16x16x32_bf16(pa, bv, ctx[ni], 0, 0, 0);
      }
    }
  }

#pragma unroll
  for (int ni = 0; ni < 8; ++ni) {
#pragma unroll
    for (int j = 0; j < 4; ++j) {
      int q = w * 16 + fg * 4 + j;
      float v = ctx[ni][j] / lrow[j];
      ctxg[(size_t)(n * QB + q) * DB + h * DHB + ni * 16 + fr] = __float2bfloat16(v);
    }
  }
}

extern "C" void kernel_launch(void* const* d_in, const int* in_sizes, int n_in,
                              void* d_out, int out_size, void* d_ws, size_t ws_size,
                              hipStream_t stream) {
  const float* x  = (const float*)d_in[0];
  const float* w1 = (const float*)d_in[1];
  const float* b1 = (const float*)d_in[2];
  const float* w2 = (const float*)d_in[3];
  const float* b2 = (const float*)d_in[4];
  const float* qt = (const float*)d_in[5];
  const float* wq = (const float*)d_in[6];
  const float* bq = (const float*)d_in[7];
  const float* wk = (const float*)d_in[8];
  const float* wv = (const float*)d_in[10];
  const float* bv = (const float*)d_in[11];
  const float* wo = (const float*)d_in[12];
  const float* bo = (const float*)d_in[13];
  const float* wg = (const float*)d_in[14];
  float* out = (float*)d_out;

  char* ws = (char*)d_ws;
  size_t off = 0;
  auto alloc = [&](size_t bytes) {
    char* p = ws + off;
    off += (bytes + 255) & ~(size_t)255;
    return p;
  };
  const size_t XE = (size_t)NB * CB * DB;
  const size_t WE = (size_t)DB * DB;
  const size_t TE = (size_t)NB * QB * DB;

  bf16* x_bf   = (bf16*)alloc(XE * 2);
  bf16* V_bf   = (bf16*)alloc(XE * 2);
  bf16* wk_bf  = (bf16*)alloc(WE * 2);
  bf16* w1T    = (bf16*)alloc(WE * 2);
  bf16* w2T    = (bf16*)alloc(WE * 2);
  bf16* wvT    = (bf16*)alloc(WE * 2);
  bf16* wqT    = (bf16*)alloc(WE * 2);
  bf16* woT    = (bf16*)alloc(WE * 2);
  bf16* tokens = (bf16*)alloc(2 * TE * 2);
  bf16* hmix   = (bf16*)alloc(TE * 2);
  bf16* ctx_bf = (bf16*)alloc(TE * 2);
  bf16* qt_bf  = (bf16*)alloc((size_t)QB * DB * 2);
  bf16* qproj  = (bf16*)alloc((size_t)QB * DB * 2);
  float* qpart = (float*)alloc((size_t)4 * QB * DB * 4);
  bf16* qk     = (bf16*)alloc((size_t)HB * QB * DB * 2);
  bf16* Sbuf   = (bf16*)alloc((size_t)NB * HB * QB * CB * 2);
  float* gates = (float*)alloc((size_t)NB * QB * 2 * 4);
  float* gsum  = (float*)alloc((size_t)NB * QB * 4);
  (void)ws_size; (void)in_sizes; (void)n_in; (void)out_size;

  k_convpool<<<dim3(2, 64, 32), 256, 0, stream>>>(x, x_bf, tokens);
  k_convert2<<<1024, 256, 0, stream>>>(
      qt, (unsigned short*)qt_bf, (int)(QB * DB / 4),
      wk, (unsigned short*)wk_bf, (int)(WE / 4));
  k_gate<<<NB * QB / 4, 256, 0, stream>>>(tokens, wg, gates, gsum);

  TP5 tp;
  tp.s[0] = w1; tp.d[0] = w1T;
  tp.s[1] = w2; tp.d[1] = w2T;
  tp.s[2] = wv; tp.d[2] = wvT;
  tp.s[3] = wq; tp.d[3] = wqT;
  tp.s[4] = wo; tp.d[4] = woT;
  k_transpose5<<<dim3(64, 64, 5), dim3(8, 32), 0, stream>>>(tp);

  // q projection: split-K x4 into f32 partials, then reduce
  k_gemm<2><<<dim3(1, 16, 4), 256, 0, stream>>>(
      qt_bf, DB, 512, wqT, DB, 512, nullptr, qpart, DB, (long long)QB * DB, QB, 512, nullptr);
  k_qreduce<<<QB * DB / 256, 256, 0, stream>>>(qpart, bq, qproj);

  // qk[h][q][d]
  k_gemm<0><<<dim3(1, 16, HB), 256, 0, stream>>>(
      qproj, DB, DHB, wk_bf, DB, DHB, nullptr, qk, DB, (long long)QB * DB, QB, DHB, nullptr);

  // V projection (single-barrier front-loaded 256^2)
  k_gemm256<0><<<dim3(512, 1, 1), 512, 0, stream>>>(
      x_bf, DB, 0, wvT, DB, 0, bv, V_bf, DB, 0, DB, 8);

  // scores (single-barrier front-loaded 256^2, batched over n)
  k_gemm256<0><<<dim3(8, 1, NB), 512, 0, stream>>>(
      qk, DB, 0, x_bf, DB, (long long)CB * DB, nullptr,
      Sbuf, CB, (long long)HB * QB * CB, DB, 2);

  // cross attention (softmax + PV, swizzled LDS)
  k_attn<<<NB * HB, 256, 0, stream>>>(Sbuf, V_bf, ctx_bf);

  // output proj -> interleaved odd rows of tokens
  k_gemm<0><<<dim3(16, 16, 1), 256, 0, stream>>>(
      ctx_bf, DB, 0, woT, DB, 0, bo, tokens + DB, 2 * DB, 0, 2048, DB, nullptr);

  // MLP1 gated-mix -> hmix
  k_gemmH<3><<<dim3(256, 1, 1), 512, 0, stream>>>(
      tokens, DB, w1T, DB, b1, hmix, DB, DB, 8, gates);

  // MLP2 -> out
  k_gemm<4><<<dim3(16, 16, 1), 256, 0, stream>>>(
      hmix, DB, 0, w2T, DB, 0, b2, out, DB, 0, 2048, DB, gsum);
}

// Round 17
// 495.967 us; speedup vs baseline: 1.0175x; 1.0175x over previous
//
#include <hip/hip_runtime.h>
#include <hip/hip_bf16.h>

typedef float f32x4 __attribute__((ext_vector_type(4)));
typedef short s16x8 __attribute__((ext_vector_type(8)));
typedef __hip_bfloat16 bf16;

#define NB 32
#define CB 512
#define DB 2048
#define QB 64
#define HB 16
#define DHB 128

static __device__ __forceinline__ void gload16(const void* g, void* l) {
  __builtin_amdgcn_global_load_lds(
      (const __attribute__((address_space(1))) void*)g,
      (__attribute__((address_space(3))) void*)l, 16, 0, 0);
}

static __device__ __forceinline__ unsigned short f2bf(float f) {
  bf16 b = __float2bfloat16(f);
  return *reinterpret_cast<unsigned short*>(&b);
}

static __device__ __forceinline__ float gelu_f(float z) {
  return 0.5f * z * (1.0f + erff(z * 0.7071067811865475f));
}

#define BAR2 do { asm volatile("" ::: "memory"); __builtin_amdgcn_s_barrier(); asm volatile("" ::: "memory"); } while (0)
#define VM2  asm volatile("s_waitcnt vmcnt(2)" ::: "memory")

// ---------------- fused convert+pool, float4 loads / ushort4 stores ----------------
__global__ void k_convpool(const float* __restrict__ x, bf16* __restrict__ x_bf,
                           bf16* __restrict__ tokens) {
  const int d0 = blockIdx.x * 1024 + threadIdx.x * 4;
  const int q = blockIdx.y, n = blockIdx.z;
  const size_t base = ((size_t)(n * CB + q * 8)) * DB + d0;
  float s0 = 0.f, s1 = 0.f, s2 = 0.f, s3 = 0.f;
#pragma unroll
  for (int j = 0; j < 8; ++j) {
    float4 v = *(const float4*)(x + base + (size_t)j * DB);
    s0 += v.x; s1 += v.y; s2 += v.z; s3 += v.w;
    ushort4 o; o.x = f2bf(v.x); o.y = f2bf(v.y); o.z = f2bf(v.z); o.w = f2bf(v.w);
    *(ushort4*)((unsigned short*)x_bf + base + (size_t)j * DB) = o;
  }
  ushort4 p;
  p.x = f2bf(s0 * 0.125f); p.y = f2bf(s1 * 0.125f);
  p.z = f2bf(s2 * 0.125f); p.w = f2bf(s3 * 0.125f);
  *(ushort4*)((unsigned short*)tokens + (size_t)2 * (n * QB + q) * DB + d0) = p;
}

// ---------------- merged convert f32 -> bf16 (two buffers, one launch) ----------------
__global__ void k_convert2(const float* __restrict__ a, unsigned short* __restrict__ oa, int na4,
                           const float* __restrict__ b, unsigned short* __restrict__ ob, int nb4) {
  int stride = gridDim.x * blockDim.x;
  int tot = na4 + nb4;
  for (int i = blockIdx.x * blockDim.x + threadIdx.x; i < tot; i += stride) {
    const float* src; unsigned short* dst; int k;
    if (i < na4) { src = a; dst = oa; k = i; } else { src = b; dst = ob; k = i - na4; }
    float4 v = ((const float4*)src)[k];
    ushort4 o;
    o.x = f2bf(v.x); o.y = f2bf(v.y); o.z = f2bf(v.z); o.w = f2bf(v.w);
    ((ushort4*)dst)[k] = o;
  }
}

// ---------------- gating (reads interleaved tokens, row 2t) ----------------
__global__ void k_gate(const bf16* __restrict__ tokens, const float* __restrict__ wg,
                       float* __restrict__ gates, float* __restrict__ gsum) {
  int t = blockIdx.x * 4 + (threadIdx.x >> 6);
  int lane = threadIdx.x & 63;
  const bf16* row = tokens + (size_t)2 * t * DB;
  float z0 = 0.f, z1 = 0.f;
  for (int d = lane; d < DB; d += 64) {
    float v = __bfloat162float(row[d]);
    z0 += v * wg[d * 2];
    z1 += v * wg[d * 2 + 1];
  }
#pragma unroll
  for (int m = 32; m; m >>= 1) { z0 += __shfl_xor(z0, m, 64); z1 += __shfl_xor(z1, m, 64); }
  if (lane == 0) {
    float mx = fmaxf(z0, z1);
    float e0 = __expf(z0 - mx), e1 = __expf(z1 - mx);
    float s = e0 + e1;
    float p0 = e0 / s, p1 = e1 / s;
    float inv = 1.0f / (p0 + p1 + 1e-6f);
    float g0 = p0 * inv, g1 = p1 * inv;
    gates[t * 2] = g0;
    gates[t * 2 + 1] = g1;
    gsum[t] = g0 + g1;
  }
}

// ---------------- batched transpose+convert: float4 loads, ushort4 stores ----------------
struct TP5 { const float* s[5]; bf16* d[5]; };
__global__ void k_transpose5(TP5 p) {
  __shared__ float t[32][33];
  const float* W = p.s[blockIdx.z];
  bf16* WT = p.d[blockIdx.z];
  int bx = blockIdx.x * 32;
  int by = blockIdx.y * 32;
  int tx = threadIdx.x;   // 0..7
  int ty = threadIdx.y;   // 0..31
  float4 v = *(const float4*)(W + (size_t)(by + ty) * DB + bx + tx * 4);
  t[ty][tx * 4 + 0] = v.x; t[ty][tx * 4 + 1] = v.y;
  t[ty][tx * 4 + 2] = v.z; t[ty][tx * 4 + 3] = v.w;
  __syncthreads();
  ushort4 o;
  o.x = f2bf(t[tx * 4 + 0][ty]);
  o.y = f2bf(t[tx * 4 + 1][ty]);
  o.z = f2bf(t[tx * 4 + 2][ty]);
  o.w = f2bf(t[tx * 4 + 3][ty]);
  *(ushort4*)((unsigned short*)WT + (size_t)(bx + ty) * DB + by + tx * 4) = o;
}

// ---------------- q-proj partial reduce ----------------
__global__ void k_qreduce(const float* __restrict__ qp, const float* __restrict__ bq,
                          bf16* __restrict__ qproj) {
  int i = blockIdx.x * 256 + threadIdx.x;
  const int S = QB * DB;
  float s = qp[i] + qp[i + S] + qp[i + 2 * S] + qp[i + 3 * S] + bq[i & (DB - 1)];
  qproj[i] = __float2bfloat16(s);
}

// ======== 256x256 GEMM, 2-barrier/K-tile, K-split phases (R3-proven schedule) ========
// EPI: 0 = bf16 out, 1 = GELU->bf16, 2 = f32 out
template <int EPI>
__global__ __launch_bounds__(512, 2) void k_gemm256(
    const bf16* __restrict__ A, int lda, long long sAb,
    const bf16* __restrict__ BT, int ldb, long long sBb,
    const float* __restrict__ bias, void* __restrict__ Cout, int ldc, long long sCb,
    int K, int ntiles) {
  __shared__ __align__(16) bf16 lds[2][2][256 * 64];

  int bid = blockIdx.x;
  { int c = gridDim.x >> 3; bid = (bid & 7) * c + (bid >> 3); }
  const int m0 = (bid / ntiles) * 256;
  const int n0 = (bid % ntiles) * 256;
  const int z = blockIdx.z;
  A += (size_t)z * sAb;
  BT += (size_t)z * sBb;

  const int tid = threadIdx.x;
  const int l = tid & 63, w = tid >> 6;
  const int wr = w >> 2, wc = w & 3;
  const int fr = l & 15, fg = l >> 4;

  const int rloc = w * 8 + (l >> 3);
  const int cswz = ((l & 7) ^ (l >> 3)) * 8;
  const bf16* Asw = A + cswz;
  const bf16* Bsw = BT + cswz;

  int rbA[4], rbB[4], ckb[2];
#pragma unroll
  for (int mi = 0; mi < 4; ++mi) rbA[mi] = (wr * 64 + mi * 16 + fr) * 128;
#pragma unroll
  for (int ni = 0; ni < 4; ++ni) rbB[ni] = ((ni >> 1) * 128 + wc * 32 + (ni & 1) * 16 + fr) * 128;
#pragma unroll
  for (int kk = 0; kk < 2; ++kk) ckb[kk] = ((kk * 4 + fg) ^ (fr & 7)) * 16;

  f32x4 acc[8][4] = {};
  s16x8 af[4], bfr[4][2];

  auto stg = [&](const bf16* srcsw, int ld, int row0, int kcol, char* dst) {
    gload16(srcsw + (size_t)(row0 + rloc) * ld + kcol, dst + w * 1024);
    gload16(srcsw + (size_t)(row0 + 64 + rloc) * ld + kcol, dst + 8192 + w * 1024);
  };

  stg(Asw, lda, m0, 0, (char*)&lds[0][0][0]);
  stg(Bsw, ldb, n0, 0, (char*)&lds[0][1][0]);
  stg(Bsw, ldb, n0 + 128, 0, (char*)&lds[0][1][0] + 16384);
  stg(Asw, lda, m0 + 128, 0, (char*)&lds[0][0][0] + 16384);
  asm volatile("s_waitcnt vmcnt(0)" ::: "memory");
  BAR2;

  const int NT = K >> 6;
  for (int t = 0; t < NT; ++t) {
    const int buf = t & 1;
    const char* Ab = (const char*)&lds[buf][0][0];
    const char* Bb = (const char*)&lds[buf][1][0];
    char* As = (char*)&lds[buf ^ 1][0][0];
    char* Bs = (char*)&lds[buf ^ 1][1][0];
    const int kn = (t + 1 < NT ? (t + 1) : 0) << 6;

    // p0: Mlo x Nall x k0
    stg(Asw, lda, m0, kn, As);
#pragma unroll
    for (int mi = 0; mi < 4; ++mi) af[mi] = *(const s16x8*)(Ab + rbA[mi] + ckb[0]);
#pragma unroll
    for (int ni = 0; ni < 4; ++ni) bfr[ni][0] = *(const s16x8*)(Bb + rbB[ni] + ckb[0]);
    __builtin_amdgcn_s_setprio(1);
#pragma unroll
    for (int mi = 0; mi < 4; ++mi)
#pragma unroll
      for (int ni = 0; ni < 4; ++ni)
        acc[mi][ni] = __builtin_amdgcn_mfma_f32_16x16x32_bf16(af[mi], bfr[ni][0], acc[mi][ni], 0, 0, 0);
    __builtin_amdgcn_s_setprio(0);
    VM2;
    BAR2;

    // p1: Mhi x Nall x k0
    stg(Bsw, ldb, n0, kn, Bs);
#pragma unroll
    for (int mi = 0; mi < 4; ++mi) af[mi] = *(const s16x8*)(Ab + 16384 + rbA[mi] + ckb[0]);
    __builtin_amdgcn_s_setprio(1);
#pragma unroll
    for (int mi = 0; mi < 4; ++mi)
#pragma unroll
      for (int ni = 0; ni < 4; ++ni)
        acc[4 + mi][ni] = __builtin_amdgcn_mfma_f32_16x16x32_bf16(af[mi], bfr[ni][0], acc[4 + mi][ni], 0, 0, 0);
    __builtin_amdgcn_s_setprio(0);

    // p2: Mlo x Nall x k1
    stg(Bsw, ldb, n0 + 128, kn, Bs + 16384);
#pragma unroll
    for (int mi = 0; mi < 4; ++mi) af[mi] = *(const s16x8*)(Ab + rbA[mi] + ckb[1]);
#pragma unroll
    for (int ni = 0; ni < 4; ++ni) bfr[ni][1] = *(const s16x8*)(Bb + rbB[ni] + ckb[1]);
    __builtin_amdgcn_s_setprio(1);
#pragma unroll
    for (int mi = 0; mi < 4; ++mi)
#pragma unroll
      for (int ni = 0; ni < 4; ++ni)
        acc[mi][ni] = __builtin_amdgcn_mfma_f32_16x16x32_bf16(af[mi], bfr[ni][1], acc[mi][ni], 0, 0, 0);
    __builtin_amdgcn_s_setprio(0);

    // p3: Mhi x Nall x k1
    stg(Asw, lda, m0 + 128, kn, As + 16384);
#pragma unroll
    for (int mi = 0; mi < 4; ++mi) af[mi] = *(const s16x8*)(Ab + 16384 + rbA[mi] + ckb[1]);
    __builtin_amdgcn_s_setprio(1);
#pragma unroll
    for (int mi = 0; mi < 4; ++mi)
#pragma unroll
      for (int ni = 0; ni < 4; ++ni)
        acc[4 + mi][ni] = __builtin_amdgcn_mfma_f32_16x16x32_bf16(af[mi], bfr[ni][1], acc[4 + mi][ni], 0, 0, 0);
    __builtin_amdgcn_s_setprio(0);
    VM2;
    BAR2;
  }

#pragma unroll
  for (int mi = 0; mi < 8; ++mi) {
    int row = m0 + (mi >> 2) * 128 + wr * 64 + (mi & 3) * 16 + fg * 4;
#pragma unroll
    for (int ni = 0; ni < 4; ++ni) {
      int col = n0 + (ni >> 1) * 128 + wc * 32 + (ni & 1) * 16 + fr;
      float bv = bias ? bias[col] : 0.f;
#pragma unroll
      for (int j = 0; j < 4; ++j) {
        float v = acc[mi][ni][j] + bv;
        size_t o = (size_t)z * sCb + (size_t)(row + j) * ldc + col;
        if (EPI == 0) {
          ((bf16*)Cout)[o] = __float2bfloat16(v);
        } else if (EPI == 1) {
          ((bf16*)Cout)[o] = __float2bfloat16(gelu_f(v));
        } else {
          ((float*)Cout)[o] = v;
        }
      }
    }
  }
}

// ======== 128x256 GEMM (BM=128), R3-pattern, 16x16 MFMA ========
template <int EPI>
__global__ __launch_bounds__(512, 2) void k_gemmH(
    const bf16* __restrict__ A, int lda,
    const bf16* __restrict__ BT, int ldb,
    const float* __restrict__ bias, void* __restrict__ Cout, int ldc,
    int K, int ntiles, const float* __restrict__ gates) {
  __shared__ __align__(16) bf16 ldsA[2][128 * 64];
  __shared__ __align__(16) bf16 ldsB[2][256 * 64];

  int bid = blockIdx.x;
  { int c = gridDim.x >> 3; bid = (bid & 7) * c + (bid >> 3); }
  const int m0 = (bid / ntiles) * 128;
  const int n0 = (bid % ntiles) * 256;

  const int tid = threadIdx.x;
  const int l = tid & 63, w = tid >> 6;
  const int wr = w >> 2, wc = w & 3;
  const int fr = l & 15, fg = l >> 4;

  const int rloc = w * 8 + (l >> 3);
  const int cswz = ((l & 7) ^ (l >> 3)) * 8;
  const bf16* Asw = A + cswz;
  const bf16* Bsw = BT + cswz;

  int rbA[4], rbB[4], ckb[2];
#pragma unroll
  for (int mi = 0; mi < 4; ++mi) rbA[mi] = (wr * 64 + mi * 16 + fr) * 128;
#pragma unroll
  for (int ni = 0; ni < 4; ++ni) rbB[ni] = ((ni >> 1) * 128 + wc * 32 + (ni & 1) * 16 + fr) * 128;
#pragma unroll
  for (int kk = 0; kk < 2; ++kk) ckb[kk] = ((kk * 4 + fg) ^ (fr & 7)) * 16;

  f32x4 acc[4][4] = {};
  s16x8 af[4], blo[2][2], bhi[2][2];

  auto stg = [&](const bf16* srcsw, int ld, int row0, int kcol, char* dst) {
    gload16(srcsw + (size_t)(row0 + rloc) * ld + kcol, dst + w * 1024);
    gload16(srcsw + (size_t)(row0 + 64 + rloc) * ld + kcol, dst + 8192 + w * 1024);
  };

  stg(Asw, lda, m0, 0, (char*)&ldsA[0][0]);
  stg(Bsw, ldb, n0, 0, (char*)&ldsB[0][0]);
  stg(Bsw, ldb, n0 + 128, 0, (char*)&ldsB[0][0] + 16384);
  asm volatile("s_waitcnt vmcnt(0)" ::: "memory");
  BAR2;

  const int NT = K >> 6;
  for (int t = 0; t < NT; ++t) {
    const int buf = t & 1;
    const char* Ab = (const char*)&ldsA[buf][0];
    const char* Bb = (const char*)&ldsB[buf][0];
    char* As = (char*)&ldsA[buf ^ 1][0];
    char* Bs = (char*)&ldsB[buf ^ 1][0];
    const int kn = (t + 1 < NT ? (t + 1) : 0) << 6;

    stg(Asw, lda, m0, kn, As);
#pragma unroll
    for (int mi = 0; mi < 4; ++mi) af[mi] = *(const s16x8*)(Ab + rbA[mi] + ckb[0]);
#pragma unroll
    for (int ni = 0; ni < 2; ++ni) blo[ni][0] = *(const s16x8*)(Bb + rbB[ni] + ckb[0]);
    __builtin_amdgcn_s_setprio(1);
#pragma unroll
    for (int mi = 0; mi < 4; ++mi)
#pragma unroll
      for (int ni = 0; ni < 2; ++ni)
        acc[mi][ni] = __builtin_amdgcn_mfma_f32_16x16x32_bf16(af[mi], blo[ni][0], acc[mi][ni], 0, 0, 0);
    __builtin_amdgcn_s_setprio(0);
    VM2;
    BAR2;

    stg(Bsw, ldb, n0, kn, Bs);
#pragma unroll
    for (int ni = 0; ni < 2; ++ni) bhi[ni][0] = *(const s16x8*)(Bb + rbB[2 + ni] + ckb[0]);
    __builtin_amdgcn_s_setprio(1);
#pragma unroll
    for (int mi = 0; mi < 4; ++mi)
#pragma unroll
      for (int ni = 0; ni < 2; ++ni)
        acc[mi][2 + ni] = __builtin_amdgcn_mfma_f32_16x16x32_bf16(af[mi], bhi[ni][0], acc[mi][2 + ni], 0, 0, 0);
    __builtin_amdgcn_s_setprio(0);

    stg(Bsw, ldb, n0 + 128, kn, Bs + 16384);
#pragma unroll
    for (int mi = 0; mi < 4; ++mi) af[mi] = *(const s16x8*)(Ab + rbA[mi] + ckb[1]);
#pragma unroll
    for (int ni = 0; ni < 2; ++ni) blo[ni][1] = *(const s16x8*)(Bb + rbB[ni] + ckb[1]);
    __builtin_amdgcn_s_setprio(1);
#pragma unroll
    for (int mi = 0; mi < 4; ++mi)
#pragma unroll
      for (int ni = 0; ni < 2; ++ni)
        acc[mi][ni] = __builtin_amdgcn_mfma_f32_16x16x32_bf16(af[mi], blo[ni][1], acc[mi][ni], 0, 0, 0);
    __builtin_amdgcn_s_setprio(0);

#pragma unroll
    for (int ni = 0; ni < 2; ++ni) bhi[ni][1] = *(const s16x8*)(Bb + rbB[2 + ni] + ckb[1]);
    __builtin_amdgcn_s_setprio(1);
#pragma unroll
    for (int mi = 0; mi < 4; ++mi)
#pragma unroll
      for (int ni = 0; ni < 2; ++ni)
        acc[mi][2 + ni] = __builtin_amdgcn_mfma_f32_16x16x32_bf16(af[mi], bhi[ni][1], acc[mi][2 + ni], 0, 0, 0);
    __builtin_amdgcn_s_setprio(0);
    VM2;
    BAR2;
  }

#pragma unroll
  for (int mi = 0; mi < 4; ++mi) {
    int row = m0 + wr * 64 + mi * 16 + fg * 4;
#pragma unroll
    for (int ni = 0; ni < 4; ++ni) {
      int col = n0 + (ni >> 1) * 128 + wc * 32 + (ni & 1) * 16 + fr;
      float bv = bias ? bias[col] : 0.f;
      if (EPI == 3) {
#pragma unroll
        for (int j = 0; j < 4; j += 2) {
          int tk = (row + j) >> 1;
          float g0 = gates[tk * 2], g1 = gates[tk * 2 + 1];
          float v0 = gelu_f(acc[mi][ni][j] + bv);
          float v1 = gelu_f(acc[mi][ni][j + 1] + bv);
          ((bf16*)Cout)[(size_t)tk * ldc + col] = __float2bfloat16(g0 * v0 + g1 * v1);
        }
      } else {
#pragma unroll
        for (int j = 0; j < 4; ++j) {
          float v = acc[mi][ni][j] + bv;
          size_t o = (size_t)(row + j) * ldc + col;
          if (EPI == 0) ((bf16*)Cout)[o] = __float2bfloat16(v);
          else ((float*)Cout)[o] = v;
        }
      }
    }
  }
}

// ---------------- 128x128 GEMM ----------------
template <int EPI>
__global__ __launch_bounds__(256) void k_gemm(
    const bf16* __restrict__ A, int lda, long long sAb,
    const bf16* __restrict__ BT, int ldb, long long sBb,
    const float* __restrict__ bias, void* __restrict__ Cout, int ldc, long long sCb,
    int M, int K, const float* __restrict__ gsum) {
  __shared__ bf16 As[128 * 32];
  __shared__ bf16 Bs[128 * 32];
  const int z = blockIdx.z;
  A += (size_t)z * sAb;
  BT += (size_t)z * sBb;
  const int tid = threadIdx.x;
  const int lane = tid & 63, w = tid >> 6;
  const int m0 = blockIdx.x * 128, n0 = blockIdx.y * 128;
  const int wm = (w >> 1) * 64, wn = (w & 1) * 64;
  f32x4 acc[4][4] = {};

  const int srow = tid >> 2;
  const int scol = (tid & 3) * 8;
  int gr0 = m0 + srow;       if (gr0 > M - 1) gr0 = M - 1;
  int gr1 = m0 + 64 + srow;  if (gr1 > M - 1) gr1 = M - 1;
  const bf16* ag0 = A + (size_t)gr0 * lda + scol;
  const bf16* ag1 = A + (size_t)gr1 * lda + scol;
  const bf16* bg0 = BT + (size_t)(n0 + srow) * ldb + scol;
  const bf16* bg1 = BT + (size_t)(n0 + 64 + srow) * ldb + scol;
  char* lA = (char*)As + w * 1024;
  char* lB = (char*)Bs + w * 1024;

  const int fr = lane & 15, fk = (lane >> 4) * 8;

  for (int k0 = 0; k0 < K; k0 += 32) {
    __syncthreads();
    gload16(ag0 + k0, lA);
    gload16(ag1 + k0, lA + 4096);
    gload16(bg0 + k0, lB);
    gload16(bg1 + k0, lB + 4096);
    __syncthreads();
    s16x8 af[4], bfr[4];
#pragma unroll
    for (int i = 0; i < 4; ++i)
      af[i] = *(const s16x8*)(As + (wm + i * 16 + fr) * 32 + fk);
#pragma unroll
    for (int i = 0; i < 4; ++i)
      bfr[i] = *(const s16x8*)(Bs + (wn + i * 16 + fr) * 32 + fk);
#pragma unroll
    for (int mi = 0; mi < 4; ++mi)
#pragma unroll
      for (int ni = 0; ni < 4; ++ni)
        acc[mi][ni] = __builtin_amdgcn_mfma_f32_16x16x32_bf16(af[mi], bfr[ni], acc[mi][ni], 0, 0, 0);
  }

  const int fg4 = (lane >> 4) * 4;
#pragma unroll
  for (int mi = 0; mi < 4; ++mi) {
#pragma unroll
    for (int ni = 0; ni < 4; ++ni) {
      int col = n0 + wn + ni * 16 + fr;
      float bv = bias ? bias[col] : 0.f;
#pragma unroll
      for (int j = 0; j < 4; ++j) {
        int r = m0 + wm + mi * 16 + fg4 + j;
        if (r >= M) continue;
        size_t o = (size_t)z * sCb + (size_t)r * ldc + col;
        if (EPI == 0) {
          ((bf16*)Cout)[o] = __float2bfloat16(acc[mi][ni][j] + bv);
        } else if (EPI == 1) {
          ((bf16*)Cout)[o] = __float2bfloat16(gelu_f(acc[mi][ni][j] + bv));
        } else if (EPI == 2) {
          ((float*)Cout)[o] = acc[mi][ni][j] + bv;
        } else {
          ((float*)Cout)[o] = acc[mi][ni][j] + gsum[r] * bv;
        }
      }
    }
  }
}

// ---------------- attention per (n,h): XOR-swizzled LDS ----------------
__global__ __launch_bounds__(256) void k_attn(
    const bf16* __restrict__ S, const bf16* __restrict__ Vg, bf16* __restrict__ ctxg) {
  __shared__ bf16 vt[128 * 64];
  __shared__ bf16 pb[4][16 * 64];
  const int nh = blockIdx.x;
  const int n = nh >> 4, h = nh & 15;
  const int tid = threadIdx.x, lane = tid & 63, w = tid >> 6;
  const int fr = lane & 15, fg = lane >> 4;

  f32x4 ctx[8] = {};
  float mrow[4], lrow[4];
#pragma unroll
  for (int j = 0; j < 4; ++j) { mrow[j] = -1e30f; lrow[j] = 0.f; }

  const bf16* Srow = S + ((size_t)n * (HB * QB) + h * QB) * CB;
  const bf16* Vbase = Vg + (size_t)(n * CB) * DB + h * DHB;
  const float SC = 0.08838834764831845f;

  const int krow = tid >> 4;
  const int kcol = (tid & 15) * 8;

  for (int c0 = 0; c0 < CB; c0 += 64) {
    __syncthreads();
#pragma unroll
    for (int jj = 0; jj < 4; ++jj) {
      int cc = jj * 16 + krow;
      s16x8 vv = *(const s16x8*)(Vbase + (size_t)(c0 + cc) * DB + kcol);
#pragma unroll
      for (int i = 0; i < 8; ++i) {
        int d = kcol + i;
        int sc = cc ^ ((((d & 7) ^ ((d >> 3) & 7))) << 3);
        vt[(size_t)d * 64 + sc] = ((const bf16*)&vv)[i];
      }
    }

    f32x4 s4[4];
#pragma unroll
    for (int ci = 0; ci < 4; ++ci)
#pragma unroll
      for (int j = 0; j < 4; ++j)
        s4[ci][j] = __bfloat162float(Srow[(size_t)(w * 16 + fg * 4 + j) * CB + c0 + ci * 16 + fr]);

#pragma unroll
    for (int j = 0; j < 4; ++j) {
      float m = fmaxf(fmaxf(s4[0][j], s4[1][j]), fmaxf(s4[2][j], s4[3][j])) * SC;
#pragma unroll
      for (int msk = 1; msk < 16; msk <<= 1) m = fmaxf(m, __shfl_xor(m, msk, 16));
      float newm = fmaxf(mrow[j], m);
      float resc = __expf(mrow[j] - newm);
      mrow[j] = newm;
      float rsum = 0.f;
      int q = fg * 4 + j;
      int qx = ((q & 7) ^ (q >> 3)) << 3;
#pragma unroll
      for (int ci = 0; ci < 4; ++ci) {
        float p = __expf(s4[ci][j] * SC - newm);
        rsum += p;
        pb[w][q * 64 + ((ci * 16 + fr) ^ qx)] = __float2bfloat16(p);
      }
#pragma unroll
      for (int msk = 1; msk < 16; msk <<= 1) rsum += __shfl_xor(rsum, msk, 16);
      lrow[j] = lrow[j] * resc + rsum;
#pragma unroll
      for (int ni = 0; ni < 8; ++ni) ctx[ni][j] = ctx[ni][j] * resc;
    }
    __syncthreads();

#pragma unroll
    for (int kk2 = 0; kk2 < 2; ++kk2) {
      int pqx = ((fr & 7) ^ (fr >> 3)) << 3;
      s16x8 pa = *(const s16x8*)(&pb[w][fr * 64 + ((kk2 * 32 + fg * 8) ^ pqx)]);
#pragma unroll
      for (int ni = 0; ni < 8; ++ni) {
        int d = ni * 16 + fr;
        int dx = (((d & 7) ^ ((d >> 3) & 7))) << 3;
        s16x8 bv = *(const s16x8*)(vt + (size_t)d * 64 + ((kk2 * 32 + fg * 8) ^ dx));
        ctx[ni] = __builtin_amdgcn_mfma_f32_16x16x32_bf16(pa, bv, ctx[ni], 0, 0, 0);
      }
    }
  }

#pragma unroll
  for (int ni = 0; ni < 8; ++ni) {
#pragma unroll
    for (int j = 0; j < 4; ++j) {
      int q = w * 16 + fg * 4 + j;
      float v = ctx[ni][j] / lrow[j];
      ctxg[(size_t)(n * QB + q) * DB + h * DHB + ni * 16 + fr] = __float2bfloat16(v);
    }
  }
}

extern "C" void kernel_launch(void* const* d_in, const int* in_sizes, int n_in,
                              void* d_out, int out_size, void* d_ws, size_t ws_size,
                              hipStream_t stream) {
  const float* x  = (const float*)d_in[0];
  const float* w1 = (const float*)d_in[1];
  const float* b1 = (const float*)d_in[2];
  const float* w2 = (const float*)d_in[3];
  const float* b2 = (const float*)d_in[4];
  const float* qt = (const float*)d_in[5];
  const float* wq = (const float*)d_in[6];
  const float* bq = (const float*)d_in[7];
  const float* wk = (const float*)d_in[8];
  const float* wv = (const float*)d_in[10];
  const float* bv = (const float*)d_in[11];
  const float* wo = (const float*)d_in[12];
  const float* bo = (const float*)d_in[13];
  const float* wg = (const float*)d_in[14];
  float* out = (float*)d_out;

  char* ws = (char*)d_ws;
  size_t off = 0;
  auto alloc = [&](size_t bytes) {
    char* p = ws + off;
    off += (bytes + 255) & ~(size_t)255;
    return p;
  };
  const size_t XE = (size_t)NB * CB * DB;
  const size_t WE = (size_t)DB * DB;
  const size_t TE = (size_t)NB * QB * DB;

  bf16* x_bf   = (bf16*)alloc(XE * 2);
  bf16* V_bf   = (bf16*)alloc(XE * 2);
  bf16* wk_bf  = (bf16*)alloc(WE * 2);
  bf16* w1T    = (bf16*)alloc(WE * 2);
  bf16* w2T    = (bf16*)alloc(WE * 2);
  bf16* wvT    = (bf16*)alloc(WE * 2);
  bf16* wqT    = (bf16*)alloc(WE * 2);
  bf16* woT    = (bf16*)alloc(WE * 2);
  bf16* tokens = (bf16*)alloc(2 * TE * 2);
  bf16* hmix   = (bf16*)alloc(TE * 2);
  bf16* ctx_bf = (bf16*)alloc(TE * 2);
  bf16* qt_bf  = (bf16*)alloc((size_t)QB * DB * 2);
  bf16* qproj  = (bf16*)alloc((size_t)QB * DB * 2);
  float* qpart = (float*)alloc((size_t)4 * QB * DB * 4);
  bf16* qk     = (bf16*)alloc((size_t)HB * QB * DB * 2);
  bf16* Sbuf   = (bf16*)alloc((size_t)NB * HB * QB * CB * 2);
  float* gates = (float*)alloc((size_t)NB * QB * 2 * 4);
  float* gsum  = (float*)alloc((size_t)NB * QB * 4);
  (void)ws_size; (void)in_sizes; (void)n_in; (void)out_size;

  k_convpool<<<dim3(2, 64, 32), 256, 0, stream>>>(x, x_bf, tokens);
  k_convert2<<<1024, 256, 0, stream>>>(
      qt, (unsigned short*)qt_bf, (int)(QB * DB / 4),
      wk, (unsigned short*)wk_bf, (int)(WE / 4));
  k_gate<<<NB * QB / 4, 256, 0, stream>>>(tokens, wg, gates, gsum);

  TP5 tp;
  tp.s[0] = w1; tp.d[0] = w1T;
  tp.s[1] = w2; tp.d[1] = w2T;
  tp.s[2] = wv; tp.d[2] = wvT;
  tp.s[3] = wq; tp.d[3] = wqT;
  tp.s[4] = wo; tp.d[4] = woT;
  k_transpose5<<<dim3(64, 64, 5), dim3(8, 32), 0, stream>>>(tp);

  // q projection: split-K x4 into f32 partials, then reduce
  k_gemm<2><<<dim3(1, 16, 4), 256, 0, stream>>>(
      qt_bf, DB, 512, wqT, DB, 512, nullptr, qpart, DB, (long long)QB * DB, QB, 512, nullptr);
  k_qreduce<<<QB * DB / 256, 256, 0, stream>>>(qpart, bq, qproj);

  // qk[h][q][d]
  k_gemm<0><<<dim3(1, 16, HB), 256, 0, stream>>>(
      qproj, DB, DHB, wk_bf, DB, DHB, nullptr, qk, DB, (long long)QB * DB, QB, DHB, nullptr);

  // V projection (proven 2-barrier 256^2)
  k_gemm256<0><<<dim3(512, 1, 1), 512, 0, stream>>>(
      x_bf, DB, 0, wvT, DB, 0, bv, V_bf, DB, 0, DB, 8);

  // scores (proven 2-barrier 256^2, batched over n)
  k_gemm256<0><<<dim3(8, 1, NB), 512, 0, stream>>>(
      qk, DB, 0, x_bf, DB, (long long)CB * DB, nullptr,
      Sbuf, CB, (long long)HB * QB * CB, DB, 2);

  // cross attention (softmax + PV, swizzled LDS)
  k_attn<<<NB * HB, 256, 0, stream>>>(Sbuf, V_bf, ctx_bf);

  // output proj -> interleaved odd rows of tokens
  k_gemm<0><<<dim3(16, 16, 1), 256, 0, stream>>>(
      ctx_bf, DB, 0, woT, DB, 0, bo, tokens + DB, 2 * DB, 0, 2048, DB, nullptr);

  // MLP1 gated-mix -> hmix
  k_gemmH<3><<<dim3(256, 1, 1), 512, 0, stream>>>(
      tokens, DB, w1T, DB, b1, hmix, DB, DB, 8, gates);

  // MLP2 -> out
  k_gemm<4><<<dim3(16, 16, 1), 256, 0, stream>>>(
      hmix, DB, 0, w2T, DB, 0, b2, out, DB, 0, 2048, DB, gsum);
}